// Round 11
// baseline (531.761 us; speedup 1.0000x reference)
//
#include <hip/hip_runtime.h>

// PointerNet: B=4, N=128, H=512, d_pair=256.
// Interface (verified):
//   inputs  f32, setup_inputs dict order
//   d_out   f32, 50,724,864 elements = [4][128][128][774]
// Per mlp g in {future(Wf1,Wf2,w3), hist1(Wh1a,Wh1b,wl1), hist2(Wh2a,Wh2b,wl2)}:
//   uv[m][c'] = sum_h P[m][h] * W1[(c'>=1024?512:0)+h][c'&1023]     (m = b*128+i)
//   y[bi,j,n] = relu( sum_k relu(u[bi][k] + v[bj][k]) * W2[k][n] )
//   p = softmax_c( sum_n y[n] * w3[n][c] )
//   out[((bi)*128+j)*774 + g*258 + {n | 256+c}] = {y | p}
//
// R19 = R18 with the B-fragment ADDRESSING UNITS bug fixed (R18 failed
// absmax 4.16: frag offsets written as 512*8/1024*8/1536*8 shorts — 8x too
// far, a leftover from the R17 short8-pointer arithmetic; w01/w10/w11 read
// wrong frags / next kt-slice). Correct offsets are +512/+1024/+1536 SHORTS
// (one frag = 64 lanes x 8 elems). Applied at prologue + both reload sites.
// Everything else unchanged from R18:
//   * BARRIERLESS kt loop: B via register ring from L2 (4 short8), reloaded
//     right after last consumer; no LDS for B; no per-kt __syncthreads.
//   * z = split-bf16 hi+lo, W2 = single truncated bf16: acc = zhi@w + zlo@w.
//   * Wave = 32j x 64n; block 512 thr = 8 waves; grid 3072 (mlp,bi,jh);
//     u in LDS read-only; head psum in separate LDS; XCD swizzle.
//
// Workspace (fused tier, ws>=27MiB):
//   uF_all  f32 [3][512][1024]   6 MiB @0     (u half, row-major)
//   vF_all  f32 [3][524288]      6 MiB @6M    (v half, 32x32 fragment-major)
//   w2fs_all u16 [3][262144]     1.5 MiB @12M (32x32 B-frag, single bf16)
//   w1f_all u16 [3][2M]         12 MiB @15M   (16x16 B-frag layout, stage1)
// Fallback (<27MiB): all-VALU path + head_kernel.

typedef __attribute__((ext_vector_type(4))) float floatx4;
typedef __attribute__((ext_vector_type(2))) float floatx2;
typedef __attribute__((ext_vector_type(16))) float floatx16;
typedef __attribute__((ext_vector_type(8))) short short8;

#define KT 16
#define LSTRIDE 68  // 64 + 4 pad (LDS bank-conflict break)
#define MB (1u << 20)

__device__ __forceinline__ void gload_lds16(const void* g, void* l) {
  __builtin_amdgcn_global_load_lds(
      (const __attribute__((address_space(1))) void*)g,
      (__attribute__((address_space(3))) void*)l, 16, 0, 0);
}

// Split 8 f32 into bf16 hi (truncated) + bf16 lo (exact remainder, truncated).
__device__ __forceinline__ void split8(const float* x, short8& hi, short8& lo) {
  unsigned hb[8], lb[8];
#pragma unroll
  for (int e = 0; e < 8; e++) {
    unsigned xb = __float_as_uint(x[e]);
    unsigned h = xb & 0xFFFF0000u;
    float l = x[e] - __uint_as_float(h);    // exact
    hb[e] = h;
    lb[e] = __float_as_uint(l) & 0xFFFF0000u;
  }
  union U { unsigned u[4]; short8 s; };
  U H, L;
#pragma unroll
  for (int p = 0; p < 4; p++) {
    H.u[p] = __builtin_amdgcn_perm(hb[2 * p + 1], hb[2 * p], 0x07060302u);
    L.u[p] = __builtin_amdgcn_perm(lb[2 * p + 1], lb[2 * p], 0x07060302u);
  }
  hi = H.s;
  lo = L.s;
}

// z = relu(u + v) for 8 k-slots -> split-bf16 hi/lo pair.
__device__ __forceinline__ void zfrag(
    const floatx4& ua, const floatx4& ub,
    const floatx4& va, const floatx4& vb,
    short8& zh, short8& zl) {
  float z[8];
#pragma unroll
  for (int e = 0; e < 4; e++) {
    z[e] = fmaxf(ua[e] + va[e], 0.0f);
    z[4 + e] = fmaxf(ub[e] + vb[e], 0.0f);
  }
  split8(z, zh, zl);
}

// ---------------------------------------------------------------------------
// prep: W1 -> 16x16 B-frag hi/lo layout (stage1, UNCHANGED);
//       W2 -> 32x32 B-frag SINGLE truncated bf16 layout (pair).
// W1F[kt(16)][NF(128)][hl(2)][lane(64)][e(8)]; lane = 16g + c holds
//   W1X[kt*32 + g*8 + e][NF*16 + c]  (u/v row split baked in).
// W2Fs[kt(32)][nf32(8)][ksub(2)][lane(64)][e(8)]; lane = 32g2 + c32 holds
//   trunc_bf16(W2[kt*32 + ksub*16 + g2*8 + e][nf32*32 + c32]).  512 KB/mlp.
// ---------------------------------------------------------------------------
__device__ __forceinline__ void prep_w1_body(
    int t, const float* __restrict__ W1, unsigned short* __restrict__ W1F) {
  int lane = t & 63;
  int nf = (t >> 6) & 127;
  int kt = t >> 13;                        // 0..15
  int g = lane >> 4, c = lane & 15;
  int n = nf * 16 + c;                     // 0..2047
  int kbase = kt * 32 + g * 8;
  const float* src = W1 + (long)((n >= 1024 ? 512 : 0) + kbase) * 1024 + (n & 1023);

  unsigned hb[8], lb[8];
#pragma unroll
  for (int e = 0; e < 8; e++) {
    float w = src[(long)e * 1024];
    unsigned wb = __float_as_uint(w);
    unsigned h = wb & 0xFFFF0000u;
    float l = w - __uint_as_float(h);
    hb[e] = h;
    lb[e] = __float_as_uint(l) & 0xFFFF0000u;
  }
  union U { unsigned u[4]; short8 s; };
  U H, L;
#pragma unroll
  for (int p = 0; p < 4; p++) {
    H.u[p] = __builtin_amdgcn_perm(hb[2 * p + 1], hb[2 * p], 0x07060302u);
    L.u[p] = __builtin_amdgcn_perm(lb[2 * p + 1], lb[2 * p], 0x07060302u);
  }
  long base = ((long)kt * 128 + nf) * 2 * 64 + lane;
  *(short8*)(W1F + (base + 0) * 8) = H.s;
  *(short8*)(W1F + (base + 64) * 8) = L.s;
}

__device__ __forceinline__ void prep_w2_single(
    int t, const float* __restrict__ W2, unsigned short* __restrict__ W2Fs) {
  int lane = t & 63;
  int ksub = (t >> 6) & 1;
  int nf32 = (t >> 7) & 7;
  int kt = t >> 10;                        // 0..31
  int g2 = lane >> 5, c32 = lane & 31;
  int n = nf32 * 32 + c32;
  int kbase = kt * 32 + ksub * 16 + g2 * 8;

  unsigned hb[8];
#pragma unroll
  for (int e = 0; e < 8; e++)
    hb[e] = __float_as_uint(W2[(long)(kbase + e) * 256 + n]);
  union U { unsigned u[4]; short8 s; } H;
#pragma unroll
  for (int p = 0; p < 4; p++)
    H.u[p] = __builtin_amdgcn_perm(hb[2 * p + 1], hb[2 * p], 0x07060302u);
  long base = (((long)kt * 8 + nf32) * 2 + ksub) * 64 + lane;
  *(short8*)(W2Fs + base * 8) = H.s;
}

// Fused prep: all 3 W1 (blocks 0..1535) + all 3 W2 (blocks 1536..1919).
__global__ __launch_bounds__(256) void prep_all(
    const float* __restrict__ Wf1, const float* __restrict__ Wh1a,
    const float* __restrict__ Wh2a, const float* __restrict__ Wf2,
    const float* __restrict__ Wh1b, const float* __restrict__ Wh2b,
    unsigned short* __restrict__ w1f_all, unsigned short* __restrict__ w2fs_all) {
  int bx = blockIdx.x;
  if (bx < 1536) {
    int mlp = bx >> 9;
    const float* W1 = (mlp == 0) ? Wf1 : (mlp == 1) ? Wh1a : Wh2a;
    prep_w1_body((bx & 511) * 256 + threadIdx.x, W1,
                 w1f_all + (long)mlp * (2 * MB));   // 4 MiB = 2M shorts
  } else {
    int bb = bx - 1536;                             // 0..383
    int mlp = bb >> 7;
    const float* W2 = (mlp == 0) ? Wf2 : (mlp == 1) ? Wh1b : Wh2b;
    prep_w2_single((bb & 127) * 256 + threadIdx.x, W2,
                   w2fs_all + (long)mlp * 262144);  // 512 KB = 256K shorts
  }
}

// ---------------------------------------------------------------------------
// stage1 core (UNCHANGED, verified): split-bf16 16x16x32 MFMA; writes uF
// (row-major) and vF (32x32 A-frag-major).
// vF flat: ((b*32+kt)*4 + jf32)*1024 + (kg*32 + (j&31))*16 + ksub*8 + e
//   holds v[b*128 + jf32*32 + (j&31)][kt*32 + ksub*16 + kg*8 + e].
// ---------------------------------------------------------------------------
__device__ __forceinline__ void stage1_core(
    int bx, const float* __restrict__ P,
    const unsigned short* __restrict__ W1F,
    float* __restrict__ uF, float* __restrict__ vF) {
  int m0 = (bx >> 4) * 16;
  int n0 = (bx & 15) * 128;
  int tid = threadIdx.x;
  int wid = tid >> 6, lane = tid & 63;
  int g = lane >> 4, r = lane & 15;
  int nw0 = n0 + wid * 32;                 // wave covers 2 n-frags

  const float* prow = P + (long)(m0 + r) * 512;

  floatx4 acc[2];
#pragma unroll
  for (int nf = 0; nf < 2; nf++) acc[nf] = (floatx4){0.f, 0.f, 0.f, 0.f};

  for (int kt = 0; kt < 16; kt++) {
    int k0 = kt * 32 + g * 8;
    float a[8];
    floatx4 a0 = *(const floatx4*)(prow + k0);
    floatx4 a1 = *(const floatx4*)(prow + k0 + 4);
#pragma unroll
    for (int e = 0; e < 4; e++) { a[e] = a0[e]; a[4 + e] = a1[e]; }
    short8 ahi, alo;
    split8(a, ahi, alo);
#pragma unroll
    for (int nf = 0; nf < 2; nf++) {
      int nfg = (nw0 >> 4) + nf;
      const unsigned short* wp = W1F + (((long)kt * 128 + nfg) * 2 * 64 + lane) * 8;
      short8 whi = *(const short8*)wp;
      short8 wlo = *(const short8*)(wp + 64 * 8);
      acc[nf] = __builtin_amdgcn_mfma_f32_16x16x32_bf16(ahi, whi, acc[nf], 0, 0, 0);
      acc[nf] = __builtin_amdgcn_mfma_f32_16x16x32_bf16(alo, whi, acc[nf], 0, 0, 0);
      acc[nf] = __builtin_amdgcn_mfma_f32_16x16x32_bf16(ahi, wlo, acc[nf], 0, 0, 0);
    }
  }
  // D: row = g*4 + reg (m within 16-tile), col = r (n within nf 16-tile)
  if (n0 < 1024) {
#pragma unroll
    for (int nf = 0; nf < 2; nf++)
#pragma unroll
      for (int reg = 0; reg < 4; reg++)
        uF[(long)(m0 + g * 4 + reg) * 1024 + nw0 + nf * 16 + r] = acc[nf][reg];
  } else {
    int kt = (nw0 - 1024) >> 5;            // wave-uniform
#pragma unroll
    for (int nf = 0; nf < 2; nf++) {
#pragma unroll
      for (int reg = 0; reg < 4; reg++) {
        int m = m0 + g * 4 + reg;
        int b = m >> 7;
        int jf = (m >> 5) & 3;
        long idx = (((long)(b * 32 + kt)) * 4 + jf) * 1024 +
                   ((r >> 3) * 32 + (m & 31)) * 16 + nf * 8 + (r & 7);
        vF[idx] = acc[nf][reg];
      }
    }
  }
}

__global__ __launch_bounds__(256) void stage1_mfma3(
    const float* __restrict__ P, const unsigned short* __restrict__ w1f_all,
    float* __restrict__ uF_all, float* __restrict__ vF_all) {
  int mlp = blockIdx.x >> 9;
  stage1_core(blockIdx.x & 511, P, w1f_all + (long)mlp * (2 * MB),
              uF_all + (long)mlp * 524288, vF_all + (long)mlp * 524288);
}

// ---------------------------------------------------------------------------
// pair kernel: BARRIERLESS 2-product 32x32x16 MFMA (zhi@w + zlo@w).
// Grid 3072 = (mlp*512 + bi)*2 + jh.  512 thr = 8 waves; wave (jw = wid>>2,
// nq = wid&3) owns m-tile jf = jh*2+jw (32 j) x 64 n (nf32 = nq*2, nq*2+1).
// B frag (nf32, ksub) lives at ((nf32*2+ksub)*64 + lane)*8 shorts within the
// kt-slice (8192 shorts/kt) -> relative to wb: +0 / +512 / +1024 / +1536
// SHORTS (R18's bug: these were *8 too large).
// ---------------------------------------------------------------------------
__global__ __launch_bounds__(512, 4) void pair_mfma3(
    const float* __restrict__ uF_all, const float* __restrict__ vF_all,
    const unsigned short* __restrict__ w2fs_all,
    const float* __restrict__ w3_0, const float* __restrict__ w3_1,
    const float* __restrict__ w3_2, float* __restrict__ out) {
  __shared__ float ulds[1024];   // u row, read-only after prologue
  __shared__ float ps[512];      // head psum: [64 rows][4 nq][2]
  int orig = blockIdx.x;                      // 3072 = 8 XCD * 384
  int id = (orig & 7) * 384 + (orig >> 3);    // bijective XCD swizzle
  int jh = id & 1;
  int bi = (id >> 1) & 511;
  int mlp = id >> 10;
  int b = bi >> 7;
  const float* w3 = (mlp == 0) ? w3_0 : (mlp == 1) ? w3_1 : w3_2;
  const float* uF = uF_all + (long)mlp * 524288;
  const float* vF = vF_all + (long)mlp * 524288;
  const unsigned short* W2Fs = w2fs_all + (long)mlp * 262144;

  int tid = threadIdx.x;
  int wid = tid >> 6;           // 0..7
  int lane = tid & 63;
  int jw = wid >> 2;            // 0..1 -> m-tile jf = jh*2 + jw
  int nq = wid & 3;             // n-quarter: cols [nq*64, +64)
  int jf = jh * 2 + jw;
  int g2 = lane >> 5;
  int c32 = lane & 31;

  // v base for this m-tile; per-kt stride 4096 floats.
  const float* vbase = vF + ((long)b * 128 + jf) * 1024 + lane * 16;
  // B base for this wave's first frag (nf32 = nq*2, ksub 0); per-kt stride
  // 8192 shorts; frag stride 512 shorts.
  const unsigned short* wb = W2Fs + ((nq * 2) * 2) * 512 + lane * 8;

  // Prologue: stage u (4 KB) via gload_lds; load v(0) + B(0) regs.
  const float* urow = uF + (long)bi * 1024;
  if (tid < 256) gload_lds16(urow + tid * 4, &ulds[tid * 4]);
  floatx4 v0 = *(const floatx4*)(vbase);
  floatx4 v1 = *(const floatx4*)(vbase + 4);
  floatx4 v2 = *(const floatx4*)(vbase + 8);
  floatx4 v3 = *(const floatx4*)(vbase + 12);
  short8 w00 = *(const short8*)(wb);           // nf0 ks0
  short8 w01 = *(const short8*)(wb + 512);     // nf0 ks1
  short8 w10 = *(const short8*)(wb + 1024);    // nf1 ks0
  short8 w11 = *(const short8*)(wb + 1536);    // nf1 ks1

  floatx16 acc[2];
#pragma unroll
  for (int nf = 0; nf < 2; nf++)
#pragma unroll
    for (int e = 0; e < 16; e++) acc[nf][e] = 0.f;

  __syncthreads();   // u resident (only barrier before epilogue)

  for (int kt = 0; kt < 32; kt++) {
    // u for this kt (LDS, read-only).
    floatx4 u0 = *(const floatx4*)&ulds[kt * 32 + g2 * 8];
    floatx4 u1 = *(const floatx4*)&ulds[kt * 32 + g2 * 8 + 4];
    floatx4 u2 = *(const floatx4*)&ulds[kt * 32 + 16 + g2 * 8];
    floatx4 u3 = *(const floatx4*)&ulds[kt * 32 + 16 + g2 * 8 + 4];
    short8 zh0, zl0, zh1, zl1;
    zfrag(u0, u1, v0, v1, zh0, zl0);       // ksub 0
    zfrag(u2, u3, v2, v3, zh1, zl1);       // ksub 1
    // v prefetch kt+1 (WAR on v regs; over-read at kt=31 stays in ws).
    {
      const float* vp = vbase + (long)(kt + 1) * 4096;
      v0 = *(const floatx4*)(vp);
      v1 = *(const floatx4*)(vp + 4);
      v2 = *(const floatx4*)(vp + 8);
      v3 = *(const floatx4*)(vp + 12);
    }
    const unsigned short* wn = wb + (long)(kt + 1) * 8192;
    __builtin_amdgcn_s_setprio(1);
    acc[0] = __builtin_amdgcn_mfma_f32_32x32x16_bf16(zh0, w00, acc[0], 0, 0, 0);
    acc[1] = __builtin_amdgcn_mfma_f32_32x32x16_bf16(zh0, w10, acc[1], 0, 0, 0);
    acc[0] = __builtin_amdgcn_mfma_f32_32x32x16_bf16(zl0, w00, acc[0], 0, 0, 0);
    acc[1] = __builtin_amdgcn_mfma_f32_32x32x16_bf16(zl0, w10, acc[1], 0, 0, 0);
    w00 = *(const short8*)(wn);                 // reload after last use
    w10 = *(const short8*)(wn + 1024);
    acc[0] = __builtin_amdgcn_mfma_f32_32x32x16_bf16(zh1, w01, acc[0], 0, 0, 0);
    acc[1] = __builtin_amdgcn_mfma_f32_32x32x16_bf16(zh1, w11, acc[1], 0, 0, 0);
    acc[0] = __builtin_amdgcn_mfma_f32_32x32x16_bf16(zl1, w01, acc[0], 0, 0, 0);
    acc[1] = __builtin_amdgcn_mfma_f32_32x32x16_bf16(zl1, w11, acc[1], 0, 0, 0);
    w01 = *(const short8*)(wn + 512);
    w11 = *(const short8*)(wn + 1536);
    __builtin_amdgcn_s_setprio(0);
  }

  // Epilogue: D col = c32 (n), row = (reg&3)+8*(reg>>2)+4*g2 (j within 32).
  // y stores + fused head: shfl-reduce over c32 (within 32-lane half),
  // psum combine across 4 nq via LDS.
  float* ob = out + (long)(bi * 128) * 774 + mlp * 258;
  floatx2 w3v[2];
#pragma unroll
  for (int nf = 0; nf < 2; nf++)
    w3v[nf] = *(const floatx2*)(w3 + (nq * 64 + nf * 32 + c32) * 2);
#pragma unroll
  for (int reg = 0; reg < 16; reg++) {
    int lrow = jw * 32 + (reg & 3) + 8 * (reg >> 2) + 4 * g2;   // 0..63
    float* orow = ob + (long)(jh * 64 + lrow) * 774 + nq * 64 + c32;
    float s0 = 0.f, s1 = 0.f;
#pragma unroll
    for (int nf = 0; nf < 2; nf++) {
      float y = acc[nf][reg];
      y = y > 0.f ? y : 0.f;
      orow[nf * 32] = y;
      s0 += y * w3v[nf][0];
      s1 += y * w3v[nf][1];
    }
#pragma unroll
    for (int off = 1; off < 32; off <<= 1) {
      s0 += __shfl_xor(s0, off, 64);
      s1 += __shfl_xor(s1, off, 64);
    }
    if (c32 == 0) {
      ps[(lrow * 4 + nq) * 2 + 0] = s0;
      ps[(lrow * 4 + nq) * 2 + 1] = s1;
    }
  }
  __syncthreads();
  if (tid < 64) {
    int lrow = tid;
    float s0 = ps[(lrow * 4 + 0) * 2] + ps[(lrow * 4 + 1) * 2] +
               ps[(lrow * 4 + 2) * 2] + ps[(lrow * 4 + 3) * 2];
    float s1 = ps[(lrow * 4 + 0) * 2 + 1] + ps[(lrow * 4 + 1) * 2 + 1] +
               ps[(lrow * 4 + 2) * 2 + 1] + ps[(lrow * 4 + 3) * 2 + 1];
    float m = fmaxf(s0, s1);
    float e0 = __expf(s0 - m), e1 = __expf(s1 - m);
    float inv = 1.0f / (e0 + e1);
    floatx2 pr;
    pr[0] = e0 * inv;
    pr[1] = e1 * inv;
    *(floatx2*)(ob + (long)(jh * 64 + lrow) * 774 + 256) = pr;   // 8B aligned
  }
}

// ---------------------------------------------------------------------------
// VALU fallback path (proven; used only if ws < 27 MiB). uv row-major 4 MiB.
// ---------------------------------------------------------------------------
__global__ __launch_bounds__(256) void stage1_valu(
    const float* __restrict__ P, const float* __restrict__ W1,
    float* __restrict__ uv) {
  __shared__ float at[KT][LSTRIDE];
  __shared__ float wt[KT][LSTRIDE];
  int bx = blockIdx.x;
  int m0 = (bx >> 5) * 64;
  int c0 = (bx & 31) * 64;
  int half = c0 >> 10;
  int ccol = c0 & 1023;
  int tid = threadIdx.x;
  int tm = tid >> 4, tn = tid & 15;
  int lm = tid >> 2;
  int lk4 = (tid & 3) * 4;
  int lkk = tid >> 4;
  int lc4 = (tid & 15) * 4;

  float acc[4][4] = {};

  for (int k0 = 0; k0 < 512; k0 += KT) {
    floatx4 pa = *(const floatx4*)(P + (long)(m0 + lm) * 512 + k0 + lk4);
    floatx4 wa = *(const floatx4*)(W1 + (long)(half * 512 + k0 + lkk) * 1024 + ccol + lc4);
    __syncthreads();
#pragma unroll
    for (int e = 0; e < 4; e++) at[lk4 + e][lm] = pa[e];
    *(floatx4*)&wt[lkk][lc4] = wa;
    __syncthreads();
#pragma unroll
    for (int kk = 0; kk < KT; kk++) {
      floatx4 av = *(const floatx4*)&at[kk][tm * 4];
      floatx4 wv = *(const floatx4*)&wt[kk][tn * 4];
#pragma unroll
      for (int mm = 0; mm < 4; mm++)
#pragma unroll
        for (int nn = 0; nn < 4; nn++)
          acc[mm][nn] += av[mm] * wv[nn];
    }
  }
#pragma unroll
  for (int mm = 0; mm < 4; mm++) {
    floatx4 o;
#pragma unroll
    for (int nn = 0; nn < 4; nn++) o[nn] = acc[mm][nn];
    *(floatx4*)(uv + (long)(m0 + tm * 4 + mm) * 2048 + c0 + tn * 4) = o;
  }
}

__global__ __launch_bounds__(256) void pair_valu(
    const float* __restrict__ uv, const float* __restrict__ W2,
    float* __restrict__ out, int mlp) {
  __shared__ float zt[KT][LSTRIDE];
  __shared__ float wt[KT][LSTRIDE];
  int bx = blockIdx.x;               // 4096 = 512 bi x 2 jh x 4 nb
  int nb = bx & 3;
  int jh = (bx >> 2) & 1;
  int bi = bx >> 3;
  int b = bi >> 7;
  int j0 = jh * 64;
  int n0 = nb * 64;
  int tid = threadIdx.x;
  int tm = tid >> 4, tn = tid & 15;
  int lj = tid >> 2;
  int lk4 = (tid & 3) * 4;
  int lkk = tid >> 4;
  int ln4 = (tid & 15) * 4;

  const float* urow = uv + (long)bi * 2048;
  const float* vrow = uv + (long)(b * 128 + j0 + lj) * 2048 + 1024;

  float acc[4][4] = {};

  for (int k0 = 0; k0 < 1024; k0 += KT) {
    floatx4 uu = *(const floatx4*)(urow + k0 + lk4);
    floatx4 vv = *(const floatx4*)(vrow + k0 + lk4);
    floatx4 wa = *(const floatx4*)(W2 + (long)(k0 + lkk) * 256 + n0 + ln4);
    __syncthreads();
#pragma unroll
    for (int e = 0; e < 4; e++) {
      float z = uu[e] + vv[e];
      zt[lk4 + e][lj] = z > 0.f ? z : 0.f;
    }
    *(floatx4*)&wt[lkk][ln4] = wa;
    __syncthreads();
#pragma unroll
    for (int kk = 0; kk < KT; kk++) {
      floatx4 zv = *(const floatx4*)&zt[kk][tm * 4];
      floatx4 wv = *(const floatx4*)&wt[kk][tn * 4];
#pragma unroll
      for (int mm = 0; mm < 4; mm++)
#pragma unroll
        for (int nn = 0; nn < 4; nn++)
          acc[mm][nn] += zv[mm] * wv[nn];
    }
  }
  float* ob = out + (long)(bi * 128 + j0) * 774 + mlp * 258 + n0 + tn * 4;
#pragma unroll
  for (int mm = 0; mm < 4; mm++) {
    float* orow = ob + (long)(tm * 4 + mm) * 774;
    floatx2 pa, pb;
    pa[0] = acc[mm][0] > 0.f ? acc[mm][0] : 0.f;
    pa[1] = acc[mm][1] > 0.f ? acc[mm][1] : 0.f;
    pb[0] = acc[mm][2] > 0.f ? acc[mm][2] : 0.f;
    pb[1] = acc[mm][3] > 0.f ? acc[mm][3] : 0.f;
    *(floatx2*)orow = pa;
    *(floatx2*)(orow + 2) = pb;
  }
}

__global__ __launch_bounds__(256) void head_kernel(
    const float* __restrict__ w3_0, const float* __restrict__ w3_1,
    const float* __restrict__ w3_2, float* out) {
  int wid = threadIdx.x >> 6, lane = threadIdx.x & 63;
  int r = blockIdx.x * 4 + wid;   // [0, 196608)
  int mlp = r >> 16;
  int row = r & 65535;
  const float* w3 = (mlp == 0) ? w3_0 : (mlp == 1) ? w3_1 : w3_2;
  const float* yp = out + (long)row * 774 + mlp * 258 + lane * 4;
  floatx2 ya = *(const floatx2*)yp;
  floatx2 yb = *(const floatx2*)(yp + 2);
  const float* wp = w3 + lane * 8;
  floatx4 wv0 = *(const floatx4*)wp;
  floatx4 wv1 = *(const floatx4*)(wp + 4);
  float s0 = ya[0] * wv0[0] + ya[1] * wv0[2] + yb[0] * wv1[0] + yb[1] * wv1[2];
  float s1 = ya[0] * wv0[1] + ya[1] * wv0[3] + yb[0] * wv1[1] + yb[1] * wv1[3];
#pragma unroll
  for (int off = 32; off > 0; off >>= 1) {
    s0 += __shfl_xor(s0, off, 64);
    s1 += __shfl_xor(s1, off, 64);
  }
  if (lane == 0) {
    float m = fmaxf(s0, s1);
    float e0 = __expf(s0 - m), e1 = __expf(s1 - m);
    float inv = 1.0f / (e0 + e1);
    floatx2 pr;
    pr[0] = e0 * inv;
    pr[1] = e1 * inv;
    *(floatx2*)(out + (long)row * 774 + mlp * 258 + 256) = pr;
  }
}

extern "C" void kernel_launch(void* const* d_in, const int* in_sizes, int n_in,
                              void* d_out, int out_size, void* d_ws, size_t ws_size,
                              hipStream_t stream) {
  const float* para = (const float*)d_in[0];
  const float* Wf1  = (const float*)d_in[1];
  const float* Wf2  = (const float*)d_in[2];
  const float* w3   = (const float*)d_in[3];
  const float* Wh1a = (const float*)d_in[4];
  const float* Wh1b = (const float*)d_in[5];
  const float* wl1  = (const float*)d_in[6];
  const float* Wh2a = (const float*)d_in[7];
  const float* Wh2b = (const float*)d_in[8];
  const float* wl2  = (const float*)d_in[9];

  float* outp = (float*)d_out;   // f32 [4*128*128][774]

  if (ws_size >= (size_t)27 * MB) {
    float* uF_all = (float*)d_ws;                                        // 6 MiB
    float* vF_all = (float*)((char*)d_ws + 6 * MB);                      // 6 MiB
    unsigned short* w2fs_all = (unsigned short*)((char*)d_ws + 12 * MB); // 1.5 MiB
    unsigned short* w1f_all = (unsigned short*)((char*)d_ws + 15 * MB);  // 12 MiB
    prep_all<<<1920, 256, 0, stream>>>(Wf1, Wh1a, Wh2a, Wf2, Wh1b, Wh2b,
                                       w1f_all, w2fs_all);
    stage1_mfma3<<<1536, 256, 0, stream>>>(para, w1f_all, uF_all, vF_all);
    pair_mfma3<<<3072, 512, 0, stream>>>(uF_all, vF_all, w2fs_all,
                                         w3, wl1, wl2, outp);
  } else {
    const float* W1s[3] = {Wf1, Wh1a, Wh2a};
    const float* W2s[3] = {Wf2, Wh1b, Wh2b};
    float* uv = (float*)d_ws;   // 4 MiB
    for (int mlp = 0; mlp < 3; mlp++) {
      stage1_valu<<<256, 256, 0, stream>>>(para, W1s[mlp], uv);
      pair_valu<<<4096, 256, 0, stream>>>(uv, W2s[mlp], outp, mlp);
    }
    head_kernel<<<49152, 256, 0, stream>>>(w3, wl1, wl2, outp);
  }
}